// Round 13
// baseline (19528.189 us; speedup 1.0000x reference)
//
#include <hip/hip_runtime.h>
#include <hip/hip_bf16.h>

#define S_LEN 40
#define NB    256
#define EDIM  1024
#define HDIM  1024
#define NBLK  256
#define NTHR  768

typedef _Float16 f16;
typedef __attribute__((ext_vector_type(8))) _Float16 f16x8;
typedef __attribute__((ext_vector_type(4))) _Float16 f16x4;
typedef __attribute__((ext_vector_type(4))) float f32x4;

__device__ __forceinline__ float sigm(float x) {
    x = fminf(fmaxf(x, -30.f), 30.f);
    return 1.f / (1.f + __expf(-x));
}
__device__ __forceinline__ float tanh_fast(float x) {
    x = fminf(fmaxf(x, -15.f), 15.f);
    float e = __expf(2.f * x);
    return (e - 1.f) / (e + 1.f);
}

// ---- system-scope (cross-XCD, L2+L1 bypass) helpers -----------------------
__device__ __forceinline__ void sysld_issue_b128(f16x8& v, const void* p) {
    asm volatile("global_load_dwordx4 %0, %1, off sc0 sc1 nt" : "=v"(v) : "v"(p));
}
__device__ __forceinline__ void sysld_issue_f32(float& v, const void* p) {
    asm volatile("global_load_dword %0, %1, off sc0 sc1 nt" : "=v"(v) : "v"(p));
}
__device__ __forceinline__ void sysld_issue_f32x4(f32x4& v, const void* p) {
    asm volatile("global_load_dwordx4 %0, %1, off sc0 sc1 nt" : "=v"(v) : "v"(p));
}
__device__ __forceinline__ void sys_wait() {
    asm volatile("s_waitcnt vmcnt(0)" ::: "memory");
    __builtin_amdgcn_sched_barrier(0);
}
__device__ __forceinline__ void sysst_f32(float* p, float v) {
    asm volatile("global_store_dword %0, %1, off sc0 sc1 nt" :: "v"(p), "v"(v) : "memory");
}
__device__ __forceinline__ void sysst_f32x4(float* p, f32x4 v) {
    asm volatile("global_store_dwordx4 %0, %1, off sc0 sc1 nt" :: "v"(p), "v"(v) : "memory");
}
__device__ __forceinline__ void sysst_f16(f16* p, f16 v) {
    union { f16 f; unsigned short s; } u; u.f = v;
    unsigned int b = u.s;
    asm volatile("global_store_short %0, %1, off sc0 sc1 nt" :: "v"(p), "v"(b) : "memory");
}

// ---- release-only single-counter barrier (registration only) --------------
__device__ __forceinline__ void gbar1(unsigned* cnt, unsigned* gen) {
    asm volatile("s_waitcnt vmcnt(0)" ::: "memory");
    __syncthreads();
    if (threadIdx.x == 0) {
        unsigned g = __hip_atomic_load(gen, __ATOMIC_RELAXED, __HIP_MEMORY_SCOPE_AGENT);
        unsigned a = __hip_atomic_fetch_add(cnt, 1u, __ATOMIC_RELEASE, __HIP_MEMORY_SCOPE_AGENT);
        if (a == NBLK - 1) {
            __hip_atomic_store(cnt, 0u, __ATOMIC_RELAXED, __HIP_MEMORY_SCOPE_AGENT);
            __hip_atomic_fetch_add(gen, 1u, __ATOMIC_RELEASE, __HIP_MEMORY_SCOPE_AGENT);
        } else {
            while (__hip_atomic_load(gen, __ATOMIC_RELAXED, __HIP_MEMORY_SCOPE_AGENT) == g)
                __builtin_amdgcn_s_sleep(2);
        }
    }
    __syncthreads();
}

// ---- two-level release-only grid barrier ----------------------------------
// sync[0]=ggen [1]=gcnt [16+16x]=arrival [256+x]=rank ctr [512],[513]=reg bar
__device__ __forceinline__ void g2bar(unsigned* sync, unsigned xcd,
                                      unsigned M, unsigned NX) {
    asm volatile("s_waitcnt vmcnt(0)" ::: "memory");
    __syncthreads();
    if (threadIdx.x == 0) {
        unsigned* ggen = sync;
        unsigned* gcnt = sync + 1;
        unsigned* xa = sync + 16 + xcd * 16;
        unsigned g = __hip_atomic_load(ggen, __ATOMIC_RELAXED, __HIP_MEMORY_SCOPE_AGENT);
        unsigned a = __hip_atomic_fetch_add(xa, 1u, __ATOMIC_RELEASE, __HIP_MEMORY_SCOPE_AGENT);
        if (a == M - 1) {
            __hip_atomic_store(xa, 0u, __ATOMIC_RELAXED, __HIP_MEMORY_SCOPE_AGENT);
            unsigned b = __hip_atomic_fetch_add(gcnt, 1u, __ATOMIC_RELEASE, __HIP_MEMORY_SCOPE_AGENT);
            if (b == NX - 1) {
                __hip_atomic_store(gcnt, 0u, __ATOMIC_RELAXED, __HIP_MEMORY_SCOPE_AGENT);
                __hip_atomic_fetch_add(ggen, 1u, __ATOMIC_RELEASE, __HIP_MEMORY_SCOPE_AGENT);
            } else {
                while (__hip_atomic_load(ggen, __ATOMIC_RELAXED, __HIP_MEMORY_SCOPE_AGENT) == g)
                    __builtin_amdgcn_s_sleep(4);
            }
        } else {
            while (__hip_atomic_load(ggen, __ATOMIC_RELAXED, __HIP_MEMORY_SCOPE_AGENT) == g)
                __builtin_amdgcn_s_sleep(4);
        }
    }
    __syncthreads();
}

__global__ void k_init_sync(unsigned* s) {
    for (int k = threadIdx.x; k < 1024; k += 256) s[k] = 0;
}

// Layout-robust probe: A[i][k]=i, B[k][j]=1/32 -> D[i][j]=i.
__device__ __forceinline__ void probe_mn(int lane, int* mrow, int* ncol) {
    f16x8 pa, pb;
#pragma unroll
    for (int e = 0; e < 8; e++) {
        pa[e] = (f16)(float)(lane & 15);
        pb[e] = (f16)0.03125f;
    }
    f32x4 pacc = {0, 0, 0, 0};
    pacc = __builtin_amdgcn_mfma_f32_16x16x32_f16(pa, pb, pacc, 0, 0, 0);
#pragma unroll
    for (int r = 0; r < 4; r++) {
        int m = (int)(pacc[r] + 0.5f);
        int cg = ((lane >> 4) << 2) + r;
        mrow[r] = m;
        ncol[r] = (m == cg) ? (lane & 15) : cg;
    }
}

// ---------------- pre-kernels ----------------------------------------------
__global__ __launch_bounds__(256) void k_cvt4(const float* __restrict__ src,
                                              f16* __restrict__ dst, int n4) {
    int i = blockIdx.x * 256 + threadIdx.x;
    if (i < n4) {
        f32x4 v = ((const f32x4*)src)[i];
        f16x4 o = {(f16)v.x, (f16)v.y, (f16)v.z, (f16)v.w};
        ((f16x4*)dst)[i] = o;
    }
}
__global__ __launch_bounds__(256) void k_copyf4(const float* __restrict__ src,
                                                float* __restrict__ dst, int n4) {
    int i = blockIdx.x * 256 + threadIdx.x;
    if (i < n4) ((f32x4*)dst)[i] = ((const f32x4*)src)[i];
}
__global__ __launch_bounds__(256) void k_embed_cvt(const int* __restrict__ tok,
                                                   const float* __restrict__ emb,
                                                   f16* __restrict__ xe) {
    int b = blockIdx.x;
    int t = threadIdx.x;
    int token = tok[b];
    f32x4 v = ((const f32x4*)(emb + (size_t)token * EDIM))[t];
    f16x4 o = {(f16)v.x, (f16)v.y, (f16)v.z, (f16)v.w};
    ((f16x4*)(xe + (size_t)b * EDIM))[t] = o;
}

// ---------------- GRU phase: 8 rows x 128 cols per block, 12 waves ---------
// cb=(bid&7)*128 (XCD-aligned weight slice), rb=(bid>>3)*8.
// wave = gate(0..5) x khalf(0..1); 8 N-tiles x 16 K-steps per wave.
__device__ void gru_phase(
    char* lds, int bid, int tid, const int* mr, const int* nc,
    const f16* __restrict__ xsrc, bool xact,
    const f16* __restrict__ hsrc, const float* __restrict__ hfsrc,
    const f16* __restrict__ wih, const f16* __restrict__ whh,
    const float* __restrict__ bih, const float* __restrict__ bhh,
    f16* ho16, float* hof, f16* o216, float* o2f) {
    const int cb = (bid & 7) * 128;
    const int rb = (bid >> 3) * 8;

    // ---- stage x (16KB) + h (16KB) into LDS, bank-swizzled ----
    {
        constexpr int TOT = 2048;      // f16x8 groups
        constexpr int IT = 3;
        f16x8 val[IT];
#pragma unroll
        for (int i = 0; i < IT; i++) {
            int c = tid + i * NTHR;
            if (c < TOT) {
                int isH = c >> 10;
                int cl = c & 1023;
                int row = cl >> 7, cc = cl & 127;
                const f16* src = (isH ? hsrc : xsrc) +
                                 (size_t)(rb + row) * 1024 + cc * 8;
                if (isH || xact) sysld_issue_b128(val[i], src);
                else             val[i] = *(const f16x8*)src;
            }
        }
        sys_wait();
#pragma unroll
        for (int i = 0; i < IT; i++) {
            int c = tid + i * NTHR;
            if (c < TOT) {
                int isH = c >> 10;
                int cl = c & 1023;
                int row = cl >> 7, cc = cl & 127;
                *(f16x8*)(lds + isH * 16384 + row * 2048 +
                          ((cc ^ row) << 4)) = val[i];
            }
        }
    }
    __syncthreads();

    // ---- K loop ----
    const int w = tid >> 6, lane = tid & 63;
    const int pair = w >> 1, kh = w & 1;
    const int gate = (pair >= 3) ? pair - 3 : pair;
    const int r0 = lane & 15, kk0 = (lane >> 4) * 8;
    const int arow = r0 & 7;
    const char* ap = lds + ((pair < 3) ? 0 : 16384) + arow * 2048;
    const f16* Bb = ((pair < 3) ? wih : whh) +
                    ((size_t)(gate * HDIM + cb + r0)) * 1024 + kh * 512 + kk0;

    f32x4 acc[8];
#pragma unroll
    for (int nt = 0; nt < 8; nt++) acc[nt] = (f32x4){0, 0, 0, 0};
    for (int k = 0; k < 512; k += 32) {
        int gidx = (kh * 512 + kk0 + k) >> 3;
        f16x8 a = *(const f16x8*)(ap + ((gidx ^ arow) << 4));
#pragma unroll
        for (int nt = 0; nt < 8; nt++) {
            f16x8 b = *(const f16x8*)(Bb + (size_t)nt * 16 * 1024 + k);
            acc[nt] = __builtin_amdgcn_mfma_f32_16x16x32_f16(a, b, acc[nt], 0, 0, 0);
        }
    }

    float* red = (float*)(lds + 32768);
    float* rw = red + w * 1024;
#pragma unroll
    for (int nt = 0; nt < 8; nt++)
#pragma unroll
        for (int r = 0; r < 4; r++)
            if (mr[r] < 8) rw[mr[r] * 128 + nt * 16 + nc[r]] = acc[nt][r];
    __syncthreads();

    // ---- epilogue: 1024 outputs (8 rows x 128 cols) ----
    {
        float hp[2];
#pragma unroll
        for (int it = 0; it < 2; it++) {
            int i = tid + it * NTHR;
            if (i < 1024) {
                int row = i >> 7, col = i & 127;
                sysld_issue_f32(hp[it], hfsrc + (size_t)(rb + row) * 1024 + cb + col);
            }
        }
        sys_wait();
#pragma unroll
        for (int it = 0; it < 2; it++) {
            int i = tid + it * NTHR;
            if (i < 1024) {
                int row = i >> 7, col = i & 127;
                int colg = cb + col, rowg = rb + row;
                float gir = red[i]          + red[1024 + i];
                float giz = red[2048 + i]   + red[3072 + i];
                float gin = red[4096 + i]   + red[5120 + i];
                float ghr = red[6144 + i]   + red[7168 + i];
                float ghz = red[8192 + i]   + red[9216 + i];
                float ghn = red[10240 + i]  + red[11264 + i];
                float r = sigm(gir + bih[colg] + ghr + bhh[colg]);
                float z = sigm(giz + bih[HDIM + colg] + ghz + bhh[HDIM + colg]);
                float n = tanh_fast(gin + bih[2 * HDIM + colg] +
                                    r * (ghn + bhh[2 * HDIM + colg]));
                float hn2 = (1.f - z) * n + z * hp[it];
                size_t idx = (size_t)rowg * 1024 + colg;
                sysst_f16(ho16 + idx, (f16)hn2);
                sysst_f32(hof + idx, hn2);
                if (o216) sysst_f16(o216 + idx, (f16)hn2);
                if (o2f)  sysst_f32(o2f + idx, hn2);
            }
        }
    }
}

// ---------------- attention phase: 256 blocks = 256 batch rows -------------
__device__ void attn_phase(
    char* lds, int bid, int tid,
    const f16* __restrict__ xe_t, const f16* __restrict__ h0,
    const f16* __restrict__ h1,
    const f16* __restrict__ attn_w, const float* __restrict__ attn_b,
    const f16* __restrict__ enc16, f16* __restrict__ appl) {
    float* logit = (float*)(lds + 131072);
    float* awls  = logit + 64;
    const int n = bid;
    const int w = tid >> 6, lane = tid & 63;

    {
        constexpr int TOT = 5504;
        constexpr int IT = (TOT + NTHR - 1) / NTHR;  // 8
        f16x8 val[IT];
#pragma unroll
        for (int i = 0; i < IT; i++) {
            int c = tid + i * NTHR;
            if (c < TOT) {
                if (c < 5120) {
                    int s = c >> 7, cc = c & 127;
                    sysld_issue_b128(val[i], enc16 + ((size_t)s * NB + n) * 1024 + cc * 8);
                } else {
                    int r = c - 5120;
                    if (r < 128) {
                        val[i] = *(const f16x8*)(xe_t + (size_t)n * 1024 + r * 8);
                    } else if (r < 256) {
                        sysld_issue_b128(val[i], h0 + (size_t)n * 1024 + (r - 128) * 8);
                    } else {
                        sysld_issue_b128(val[i], h1 + (size_t)n * 1024 + (r - 256) * 8);
                    }
                }
            }
        }
        sys_wait();
#pragma unroll
        for (int i = 0; i < IT; i++) {
            int c = tid + i * NTHR;
            if (c < TOT) {
                if (c < 5120) *(f16x8*)(lds + c * 16) = val[i];
                else          *(f16x8*)(lds + 81920 + (c - 5120) * 16) = val[i];
            }
        }
    }
    __syncthreads();

    if (w < 10) {
#pragma unroll
        for (int si = 0; si < 4; si++) {
            int s = w * 4 + si;
            const f16* wrow = attn_w + (size_t)s * 3072;
            float acc = 0.f;
#pragma unroll
            for (int jj = 0; jj < 6; jj++) {
                int j = lane + jj * 64;
                f16x8 a = *(const f16x8*)(lds + 81920 + j * 16);
                f16x8 b = *(const f16x8*)(wrow + j * 8);
#pragma unroll
                for (int e = 0; e < 8; e++)
                    acc = fmaf((float)a[e], (float)b[e], acc);
            }
            for (int o = 32; o; o >>= 1) acc += __shfl_down(acc, o);
            if (lane == 0) logit[s] = acc + attn_b[s];
        }
    }
    __syncthreads();

    if (w == 0) {
        float v = (lane < S_LEN) ? logit[lane] : -1e30f;
        float m = v;
        for (int o = 32; o; o >>= 1) m = fmaxf(m, __shfl_xor(m, o));
        float e = (lane < S_LEN) ? __expf(v - m) : 0.f;
        float sum = e;
        for (int o = 32; o; o >>= 1) sum += __shfl_xor(sum, o);
        if (lane < S_LEN) awls[lane] = e / sum;
    }
    __syncthreads();

    for (int col = tid; col < 1024; col += NTHR) {
        float acc = 0.f;
#pragma unroll
        for (int s = 0; s < S_LEN; s++)
            acc = fmaf(awls[s], (float)*(const f16*)(lds + s * 2048 + col * 2), acc);
        sysst_f16(appl + (size_t)n * 1024 + col, (f16)acc);
    }
}

// ---------------- comb phase: 8 rows x 128 cols per block ------------------
__device__ void comb_phase(
    char* lds, int bid, int tid, const int* mr, const int* nc,
    const f16* __restrict__ xe_t, const f16* __restrict__ appl,
    const f16* __restrict__ Bw, const float* __restrict__ bias,
    f16* __restrict__ Cout) {
    const int cb = (bid & 7) * 128;
    const int rb = (bid >> 3) * 8;

    // ---- stage A = [xe (cached) | appl (sc1)]: 8 rows x 4KB = 32KB ----
    {
        constexpr int TOT = 2048;
        constexpr int IT = 3;
        f16x8 val[IT];
#pragma unroll
        for (int i = 0; i < IT; i++) {
            int c = tid + i * NTHR;
            if (c < TOT) {
                int row = c >> 8, cc = c & 255;
                if (cc < 128)
                    val[i] = *(const f16x8*)(xe_t + (size_t)(rb + row) * 1024 + cc * 8);
                else
                    sysld_issue_b128(val[i], appl + (size_t)(rb + row) * 1024 + (cc - 128) * 8);
            }
        }
        sys_wait();
#pragma unroll
        for (int i = 0; i < IT; i++) {
            int c = tid + i * NTHR;
            if (c < TOT) {
                int row = c >> 8, cc = c & 255;
                *(f16x8*)(lds + row * 4096 + ((cc ^ row) << 4)) = val[i];
            }
        }
    }
    __syncthreads();

    const int w = tid >> 6, lane = tid & 63;
    const int r0 = lane & 15, kk0 = (lane >> 4) * 8;
    const int arow = r0 & 7;
    const int c0 = (w * 64) / 12, c1 = ((w + 1) * 64) / 12;
    const char* ap = lds + arow * 4096;
    const f16* Bb = Bw + (size_t)(cb + r0) * 2048 + kk0;

    f32x4 acc[8];
#pragma unroll
    for (int nt = 0; nt < 8; nt++) acc[nt] = (f32x4){0, 0, 0, 0};
    for (int c = c0; c < c1; c++) {
        int k = c * 32;
        int gidx = (k + kk0) >> 3;
        f16x8 a = *(const f16x8*)(ap + ((gidx ^ arow) << 4));
#pragma unroll
        for (int nt = 0; nt < 8; nt++) {
            f16x8 b = *(const f16x8*)(Bb + (size_t)nt * 16 * 2048 + k);
            acc[nt] = __builtin_amdgcn_mfma_f32_16x16x32_f16(a, b, acc[nt], 0, 0, 0);
        }
    }

    float* red = (float*)(lds + 32768);
    float* rw = red + w * 1024;
#pragma unroll
    for (int nt = 0; nt < 8; nt++)
#pragma unroll
        for (int r = 0; r < 4; r++)
            if (mr[r] < 8) rw[mr[r] * 128 + nt * 16 + nc[r]] = acc[nt][r];
    __syncthreads();

#pragma unroll
    for (int it = 0; it < 2; it++) {
        int i = tid + it * NTHR;
        if (i < 1024) {
            float s = 0.f;
#pragma unroll
            for (int p = 0; p < 12; p++) s += red[p * 1024 + i];
            int row = i >> 7, col = i & 127;
            s += bias[cb + col];
            s = fmaxf(s, 0.f);
            sysst_f16(Cout + (size_t)(rb + row) * 1024 + cb + col, (f16)s);
        }
    }
}

// ---------------- the mega kernel ------------------------------------------
__global__ __launch_bounds__(NTHR, 3) void k_mega(
    const f16* __restrict__ xe,
    f16* h16, float* hf,
    const f16* __restrict__ w_eih, const f16* __restrict__ w_ehh,
    const float* __restrict__ enc_bih, const float* __restrict__ enc_bhh,
    const f16* __restrict__ w_dih, const f16* __restrict__ w_dhh,
    const float* __restrict__ dec_bih, const float* __restrict__ dec_bhh,
    const f16* __restrict__ w_attn, const float* __restrict__ attn_b,
    const f16* __restrict__ w_comb, const float* __restrict__ comb_b,
    f16* enc16, f16* appl, f16* xcur,
    float* out, unsigned* sync) {
    __shared__ char smem[131584];
    __shared__ unsigned s_meta[4];
    char* lds = smem;
    const int bid = blockIdx.x;
    const int tid = threadIdx.x;
    const int lane = tid & 63;
    const size_t NH = (size_t)NB * HDIM;

    int mr[4], nc[4];
    probe_mn(lane, mr, nc);

    // ---- registration (for two-level barrier) ----
    if (tid == 0) {
        unsigned x;
        asm volatile("s_getreg_b32 %0, hwreg(20, 0, 32)" : "=s"(x));
        x &= 7;
        __hip_atomic_fetch_add(sync + 256 + x, 1u,
                               __ATOMIC_RELAXED, __HIP_MEMORY_SCOPE_AGENT);
        s_meta[0] = x;
    }
    __syncthreads();
    gbar1(sync + 512, sync + 513);
    if (tid == 0) {
        unsigned M = __hip_atomic_load(sync + 256 + s_meta[0],
                                       __ATOMIC_RELAXED, __HIP_MEMORY_SCOPE_AGENT);
        unsigned nx = 0;
        for (int i = 0; i < 8; i++)
            nx += (__hip_atomic_load(sync + 256 + i, __ATOMIC_RELAXED,
                                     __HIP_MEMORY_SCOPE_AGENT) > 0) ? 1u : 0u;
        s_meta[2] = M; s_meta[3] = nx;
    }
    __syncthreads();
    const unsigned xcd = s_meta[0], M = s_meta[2], NX = s_meta[3];

    f16* h0b[2] = { h16, h16 + 2 * NH };
    f16* h1b[2] = { h16 + NH, h16 + 3 * NH };
    float* h0f[2] = { hf, hf + 2 * NH };
    float* h1f[2] = { hf + NH, hf + 3 * NH };

    // ---- encoder ----
    for (int t = 0; t < S_LEN; t++) {
        int p = t & 1;
        gru_phase(lds, bid, tid, mr, nc,
                  xe + (size_t)t * NB * EDIM, false,
                  h0b[p], h0f[p],
                  w_eih, w_ehh, enc_bih, enc_bhh,
                  h0b[p ^ 1], h0f[p ^ 1], (f16*)nullptr, (float*)nullptr);
        g2bar(sync, xcd, M, NX);
        gru_phase(lds, bid, tid, mr, nc,
                  h0b[p ^ 1], true,
                  h1b[p], h1f[p],
                  w_eih + (size_t)3 * HDIM * EDIM, w_ehh + (size_t)3 * HDIM * HDIM,
                  enc_bih + 3 * HDIM, enc_bhh + 3 * HDIM,
                  h1b[p ^ 1], h1f[p ^ 1], enc16 + (size_t)t * NH, (float*)nullptr);
        g2bar(sync, xcd, M, NX);
    }

    // ---- decoder ----
    for (int t = 0; t < S_LEN; t++) {
        int p = t & 1;
        attn_phase(lds, bid, tid,
                   xe + (size_t)t * NB * EDIM, h0b[p], h1b[p],
                   w_attn, attn_b, enc16, appl);
        g2bar(sync, xcd, M, NX);
        comb_phase(lds, bid, tid, mr, nc,
                   xe + (size_t)t * NB * EDIM, appl, w_comb, comb_b, xcur);
        g2bar(sync, xcd, M, NX);
        gru_phase(lds, bid, tid, mr, nc,
                  xcur, true,
                  h0b[p], h0f[p],
                  w_dih, w_dhh, dec_bih, dec_bhh,
                  h0b[p ^ 1], h0f[p ^ 1], (f16*)nullptr, (float*)nullptr);
        g2bar(sync, xcd, M, NX);
        gru_phase(lds, bid, tid, mr, nc,
                  h0b[p ^ 1], true,
                  h1b[p], h1f[p],
                  w_dih + (size_t)3 * HDIM * HDIM, w_dhh + (size_t)3 * HDIM * HDIM,
                  dec_bih + 3 * HDIM, dec_bhh + 3 * HDIM,
                  h1b[p ^ 1], h1f[p ^ 1], (f16*)nullptr, out + (size_t)t * NH);
        g2bar(sync, xcd, M, NX);
    }

    // ---- hT tail ----
    if (tid < 512) {
        size_t idx = (size_t)bid * 512 + tid;
        f32x4 v;
        sysld_issue_f32x4(v, hf + idx * 4);
        sys_wait();
        sysst_f32x4(out + (size_t)S_LEN * NH + idx * 4, v);
    }
}

extern "C" void kernel_launch(void* const* d_in, const int* in_sizes, int n_in,
                              void* d_out, int out_size, void* d_ws, size_t ws_size,
                              hipStream_t stream) {
    const int*   tokens   = (const int*)d_in[0];
    const float* hidden   = (const float*)d_in[1];
    const float* emb      = (const float*)d_in[2];
    const float* enc_wih  = (const float*)d_in[3];
    const float* enc_whh  = (const float*)d_in[4];
    const float* enc_bih  = (const float*)d_in[5];
    const float* enc_bhh  = (const float*)d_in[6];
    const float* dec_wih  = (const float*)d_in[7];
    const float* dec_whh  = (const float*)d_in[8];
    const float* dec_bih  = (const float*)d_in[9];
    const float* dec_bhh  = (const float*)d_in[10];
    const float* attn_w   = (const float*)d_in[11];
    const float* attn_b   = (const float*)d_in[12];
    const float* comb_w   = (const float*)d_in[13];
    const float* comb_b   = (const float*)d_in[14];
    float* out = (float*)d_out;

    const size_t NH = (size_t)NB * HDIM;             // 262144
    const size_t WSZ = (size_t)2 * 3 * HDIM * EDIM;  // 6291456

    float* hf = (float*)d_ws;                        // 4*NH f32
    f16* wp = (f16*)(hf + 4 * NH);
    f16 *w_eih = wp;  wp += WSZ;
    f16 *w_ehh = wp;  wp += WSZ;
    f16 *w_dih = wp;  wp += WSZ;
    f16 *w_dhh = wp;  wp += WSZ;
    f16 *w_comb = wp; wp += (size_t)HDIM * 2048;
    f16 *w_attn = wp; wp += (size_t)S_LEN * 3072;
    f16 *xe = wp;     wp += (size_t)S_LEN * NB * EDIM;
    f16 *enc16 = wp;  wp += (size_t)S_LEN * NH;
    f16 *h16 = wp;    wp += 4 * NH;
    f16 *appl = wp;   wp += NH;
    f16 *xcur = wp;   wp += NH;
    unsigned* syncp = (unsigned*)((((uintptr_t)wp) + 255) & ~(uintptr_t)255);

    k_init_sync<<<1, 256, 0, stream>>>(syncp);

    k_cvt4<<<(int)(WSZ / 4 / 256), 256, 0, stream>>>(enc_wih, w_eih, (int)(WSZ / 4));
    k_cvt4<<<(int)(WSZ / 4 / 256), 256, 0, stream>>>(enc_whh, w_ehh, (int)(WSZ / 4));
    k_cvt4<<<(int)(WSZ / 4 / 256), 256, 0, stream>>>(dec_wih, w_dih, (int)(WSZ / 4));
    k_cvt4<<<(int)(WSZ / 4 / 256), 256, 0, stream>>>(dec_whh, w_dhh, (int)(WSZ / 4));
    k_cvt4<<<(int)(HDIM * 2048 / 4 / 256), 256, 0, stream>>>(comb_w, w_comb,
                                                             HDIM * 2048 / 4);
    k_cvt4<<<(S_LEN * 3072 / 4 + 255) / 256, 256, 0, stream>>>(attn_w, w_attn,
                                                               S_LEN * 3072 / 4);
    k_embed_cvt<<<S_LEN * NB, 256, 0, stream>>>(tokens, emb, xe);
    k_cvt4<<<(int)(2 * NH / 4 / 256), 256, 0, stream>>>(hidden, h16, (int)(2 * NH / 4));
    k_copyf4<<<(int)(2 * NH / 4 / 256), 256, 0, stream>>>(hidden, hf, (int)(2 * NH / 4));

    k_mega<<<NBLK, NTHR, 0, stream>>>(
        xe, h16, hf,
        w_eih, w_ehh, enc_bih, enc_bhh,
        w_dih, w_dhh, dec_bih, dec_bhh,
        w_attn, attn_b, w_comb, comb_b,
        enc16, appl, xcur, out, syncp);
}

// Round 14
// 5611.612 us; speedup vs baseline: 3.4800x; 3.4800x over previous
//
#include <hip/hip_runtime.h>
#include <hip/hip_bf16.h>

#define S_LEN 40
#define NB    256
#define EDIM  1024
#define HDIM  1024
#define NBLK  256
#define NTHR  768

typedef _Float16 f16;
typedef __attribute__((ext_vector_type(8))) _Float16 f16x8;
typedef __attribute__((ext_vector_type(4))) _Float16 f16x4;
typedef __attribute__((ext_vector_type(4))) float f32x4;

__device__ __forceinline__ float sigm(float x) {
    x = fminf(fmaxf(x, -30.f), 30.f);
    return 1.f / (1.f + __expf(-x));
}
__device__ __forceinline__ float tanh_fast(float x) {
    x = fminf(fmaxf(x, -15.f), 15.f);
    float e = __expf(2.f * x);
    return (e - 1.f) / (e + 1.f);
}

// ---- system-scope (cross-XCD, L2-bypass, LLC-allocating) helpers ----------
__device__ __forceinline__ void sysld_issue_f32(float& v, const void* p) {
    asm volatile("global_load_dword %0, %1, off sc0 sc1" : "=v"(v) : "v"(p));
}
__device__ __forceinline__ void sysld_issue_f32x4(f32x4& v, const void* p) {
    asm volatile("global_load_dwordx4 %0, %1, off sc0 sc1" : "=v"(v) : "v"(p));
}
__device__ __forceinline__ void sys_wait() {
    asm volatile("s_waitcnt vmcnt(0)" ::: "memory");
    __builtin_amdgcn_sched_barrier(0);
}
__device__ __forceinline__ void sysst_f32(float* p, float v) {
    asm volatile("global_store_dword %0, %1, off sc0 sc1" :: "v"(p), "v"(v) : "memory");
}
__device__ __forceinline__ void sysst_f32x4(float* p, f32x4 v) {
    asm volatile("global_store_dwordx4 %0, %1, off sc0 sc1" :: "v"(p), "v"(v) : "memory");
}
__device__ __forceinline__ void sysst_f16(f16* p, f16 v) {
    union { f16 f; unsigned short s; } u; u.f = v;
    unsigned int b = u.s;
    asm volatile("global_store_short %0, %1, off sc0 sc1" :: "v"(p), "v"(b) : "memory");
}

// ---- release-only single-counter barrier (registration only) --------------
__device__ __forceinline__ void gbar1(unsigned* cnt, unsigned* gen) {
    asm volatile("s_waitcnt vmcnt(0)" ::: "memory");
    __syncthreads();
    if (threadIdx.x == 0) {
        unsigned g = __hip_atomic_load(gen, __ATOMIC_RELAXED, __HIP_MEMORY_SCOPE_AGENT);
        unsigned a = __hip_atomic_fetch_add(cnt, 1u, __ATOMIC_RELEASE, __HIP_MEMORY_SCOPE_AGENT);
        if (a == NBLK - 1) {
            __hip_atomic_store(cnt, 0u, __ATOMIC_RELAXED, __HIP_MEMORY_SCOPE_AGENT);
            __hip_atomic_fetch_add(gen, 1u, __ATOMIC_RELEASE, __HIP_MEMORY_SCOPE_AGENT);
        } else {
            while (__hip_atomic_load(gen, __ATOMIC_RELAXED, __HIP_MEMORY_SCOPE_AGENT) == g)
                __builtin_amdgcn_s_sleep(2);
        }
    }
    __syncthreads();
}

// ---- two-level release-only grid barrier ----------------------------------
__device__ __forceinline__ void g2bar(unsigned* sync, unsigned xcd,
                                      unsigned M, unsigned NX) {
    asm volatile("s_waitcnt vmcnt(0)" ::: "memory");
    __syncthreads();
    if (threadIdx.x == 0) {
        unsigned* ggen = sync;
        unsigned* gcnt = sync + 1;
        unsigned* xa = sync + 16 + xcd * 16;
        unsigned g = __hip_atomic_load(ggen, __ATOMIC_RELAXED, __HIP_MEMORY_SCOPE_AGENT);
        unsigned a = __hip_atomic_fetch_add(xa, 1u, __ATOMIC_RELEASE, __HIP_MEMORY_SCOPE_AGENT);
        if (a == M - 1) {
            __hip_atomic_store(xa, 0u, __ATOMIC_RELAXED, __HIP_MEMORY_SCOPE_AGENT);
            unsigned b = __hip_atomic_fetch_add(gcnt, 1u, __ATOMIC_RELEASE, __HIP_MEMORY_SCOPE_AGENT);
            if (b == NX - 1) {
                __hip_atomic_store(gcnt, 0u, __ATOMIC_RELAXED, __HIP_MEMORY_SCOPE_AGENT);
                __hip_atomic_fetch_add(ggen, 1u, __ATOMIC_RELEASE, __HIP_MEMORY_SCOPE_AGENT);
            } else {
                while (__hip_atomic_load(ggen, __ATOMIC_RELAXED, __HIP_MEMORY_SCOPE_AGENT) == g)
                    __builtin_amdgcn_s_sleep(4);
            }
        } else {
            while (__hip_atomic_load(ggen, __ATOMIC_RELAXED, __HIP_MEMORY_SCOPE_AGENT) == g)
                __builtin_amdgcn_s_sleep(4);
        }
    }
    __syncthreads();
}

__global__ void k_init_sync(unsigned* s) {
    for (int k = threadIdx.x; k < 1024; k += 256) s[k] = 0;
}

// Layout-robust probe: A[i][k]=i, B[k][j]=1/32 -> D[i][j]=i.
__device__ __forceinline__ void probe_mn(int lane, int* mrow, int* ncol) {
    f16x8 pa, pb;
#pragma unroll
    for (int e = 0; e < 8; e++) {
        pa[e] = (f16)(float)(lane & 15);
        pb[e] = (f16)0.03125f;
    }
    f32x4 pacc = {0, 0, 0, 0};
    pacc = __builtin_amdgcn_mfma_f32_16x16x32_f16(pa, pb, pacc, 0, 0, 0);
#pragma unroll
    for (int r = 0; r < 4; r++) {
        int m = (int)(pacc[r] + 0.5f);
        int cg = ((lane >> 4) << 2) + r;
        mrow[r] = m;
        ncol[r] = (m == cg) ? (lane & 15) : cg;
    }
}

// ---------------- pre-kernels ----------------------------------------------
__global__ __launch_bounds__(256) void k_cvt4(const float* __restrict__ src,
                                              f16* __restrict__ dst, int n4) {
    int i = blockIdx.x * 256 + threadIdx.x;
    if (i < n4) {
        f32x4 v = ((const f32x4*)src)[i];
        f16x4 o = {(f16)v.x, (f16)v.y, (f16)v.z, (f16)v.w};
        ((f16x4*)dst)[i] = o;
    }
}
__global__ __launch_bounds__(256) void k_copyf4(const float* __restrict__ src,
                                                float* __restrict__ dst, int n4) {
    int i = blockIdx.x * 256 + threadIdx.x;
    if (i < n4) ((f32x4*)dst)[i] = ((const f32x4*)src)[i];
}
__global__ __launch_bounds__(256) void k_embed_cvt(const int* __restrict__ tok,
                                                   const float* __restrict__ emb,
                                                   f16* __restrict__ xe) {
    int b = blockIdx.x;
    int t = threadIdx.x;
    int token = tok[b];
    f32x4 v = ((const f32x4*)(emb + (size_t)token * EDIM))[t];
    f16x4 o = {(f16)v.x, (f16)v.y, (f16)v.z, (f16)v.w};
    ((f16x4*)(xe + (size_t)b * EDIM))[t] = o;
}

// ---------------- GRU phase: 256 blocks, 32x32 tiles, 12 waves -------------
// Single-assignment chains: x/h consumed via PLAIN cached loads (safe: each
// chain buffer written exactly once per launch; dispatch acquire invalidated
// any prior-launch L2 lines). Producers store through to LLC via sc1.
__device__ void gru_phase(
    char* lds, int bid, int tid, const int* mr, const int* nc,
    const f16* __restrict__ xsrc,
    const f16* __restrict__ hsrc, const float* __restrict__ hfsrc,
    const f16* __restrict__ wih, const f16* __restrict__ whh,
    const float* __restrict__ bih, const float* __restrict__ bhh,
    f16* ho16, float* hof, float* o2f) {
    const int cb = (bid & 31) * 32;
    const int rb = (bid >> 5) * 32;

    // ---- stage A (x 64KB + h 64KB) into LDS, swizzled (plain loads) ----
    {
        constexpr int TOT = 8192;
        constexpr int IT = (TOT + NTHR - 1) / NTHR;   // 11
        f16x8 val[IT];
#pragma unroll
        for (int i = 0; i < IT; i++) {
            int c = tid + i * NTHR;
            if (c < TOT) {
                int isH = c >> 12;
                int cl = c & 4095;
                int row = cl >> 7, cc = cl & 127;
                const f16* src = (isH ? hsrc : xsrc) +
                                 (size_t)(rb + row) * 1024 + cc * 8;
                val[i] = *(const f16x8*)src;
            }
        }
#pragma unroll
        for (int i = 0; i < IT; i++) {
            int c = tid + i * NTHR;
            if (c < TOT) {
                int isH = c >> 12;
                int cl = c & 4095;
                int row = cl >> 7, cc = cl & 127;
                *(f16x8*)(lds + isH * 65536 + row * 2048 +
                          ((cc ^ (row & 7)) << 4)) = val[i];
            }
        }
    }
    __syncthreads();

    // ---- K loop: A from LDS, B (weights) from L2-hot global ----
    const int w = tid >> 6, lane = tid & 63;
    const int pair = w >> 1, kh = w & 1;
    const int gate = (pair >= 3) ? pair - 3 : pair;
    const int r0 = lane & 15, kk0 = (lane >> 4) * 8;
    const f16* B = ((pair < 3) ? wih : whh) + ((size_t)gate * HDIM + cb) * 1024;
    const f16* B0 = B + (size_t)r0 * 1024 + kk0 + kh * 512;
    const f16* B1 = B + (size_t)(r0 + 16) * 1024 + kk0 + kh * 512;
    const int abase = (pair < 3) ? 0 : 65536;
    const int swz = r0 & 7;
    const char* a0p = lds + abase + r0 * 2048;
    const char* a1p = lds + abase + (r0 + 16) * 2048;

    f32x4 acc00 = {0,0,0,0}, acc01 = {0,0,0,0}, acc10 = {0,0,0,0}, acc11 = {0,0,0,0};
#pragma unroll 4
    for (int k = 0; k < 512; k += 32) {
        int g = (kh * 512 + kk0 + k) >> 3;
        int off = (g ^ swz) << 4;
        f16x8 a0 = *(const f16x8*)(a0p + off);
        f16x8 a1 = *(const f16x8*)(a1p + off);
        f16x8 b0 = *(const f16x8*)(B0 + k);
        f16x8 b1 = *(const f16x8*)(B1 + k);
        acc00 = __builtin_amdgcn_mfma_f32_16x16x32_f16(a0, b0, acc00, 0, 0, 0);
        acc01 = __builtin_amdgcn_mfma_f32_16x16x32_f16(a0, b1, acc01, 0, 0, 0);
        acc10 = __builtin_amdgcn_mfma_f32_16x16x32_f16(a1, b0, acc10, 0, 0, 0);
        acc11 = __builtin_amdgcn_mfma_f32_16x16x32_f16(a1, b1, acc11, 0, 0, 0);
    }
    __syncthreads();

    float* red = (float*)lds;
    float* rw = red + w * 1024;
#pragma unroll
    for (int r = 0; r < 4; r++) {
        rw[mr[r] * 32 + nc[r]]             = acc00[r];
        rw[mr[r] * 32 + nc[r] + 16]        = acc01[r];
        rw[(mr[r] + 16) * 32 + nc[r]]      = acc10[r];
        rw[(mr[r] + 16) * 32 + nc[r] + 16] = acc11[r];
    }
    __syncthreads();

    // ---- epilogue ----
    {
        float hp[2];
#pragma unroll
        for (int it = 0; it < 2; it++) {
            int i = tid + it * NTHR;
            if (i < 1024) {
                int rr = i >> 5, ccn = i & 31;
                sysld_issue_f32(hp[it], hfsrc + (size_t)(rb + rr) * HDIM + cb + ccn);
            }
        }
        sys_wait();
#pragma unroll
        for (int it = 0; it < 2; it++) {
            int i = tid + it * NTHR;
            if (i < 1024) {
                int rr = i >> 5, ccn = i & 31;
                int col = cb + ccn;
                int row = rb + rr;
                float gir = red[i]         + red[1024 + i];
                float giz = red[2048 + i]  + red[3072 + i];
                float gin = red[4096 + i]  + red[5120 + i];
                float ghr = red[6144 + i]  + red[7168 + i];
                float ghz = red[8192 + i]  + red[9216 + i];
                float ghn = red[10240 + i] + red[11264 + i];
                float r = sigm(gir + bih[col] + ghr + bhh[col]);
                float z = sigm(giz + bih[HDIM + col] + ghz + bhh[HDIM + col]);
                float n = tanh_fast(gin + bih[2 * HDIM + col] +
                                    r * (ghn + bhh[2 * HDIM + col]));
                float hn2 = (1.f - z) * n + z * hp[it];
                size_t idx = (size_t)row * HDIM + col;
                sysst_f16(ho16 + idx, (f16)hn2);
                sysst_f32(hof + idx, hn2);
                if (o2f) o2f[idx] = hn2;   // plain store (kernel-end flush)
            }
        }
    }
}

// ---------------- attention phase: 256 blocks = 256 batch rows -------------
__device__ void attn_phase(
    char* lds, int bid, int tid,
    const f16* __restrict__ xe_t, const f16* __restrict__ h0,
    const f16* __restrict__ h1,
    const f16* __restrict__ attn_w, const float* __restrict__ attn_b,
    const f16* __restrict__ enc16, f16* __restrict__ appl) {
    float* logit = (float*)(lds + 131072);
    float* awls  = logit + 64;
    const int n = bid;
    const int w = tid >> 6, lane = tid & 63;
    const size_t nrow = (size_t)n * 1024;

    // ---- stage enc rows (80KB) + x/h0/h1 rows (6KB) — ALL plain cached ----
    {
        constexpr int TOT = 5504;
        constexpr int IT = (TOT + NTHR - 1) / NTHR;  // 8
        f16x8 val[IT];
#pragma unroll
        for (int i = 0; i < IT; i++) {
            int c = tid + i * NTHR;
            if (c < TOT) {
                if (c < 5120) {
                    int s = c >> 7, cc = c & 127;
                    val[i] = *(const f16x8*)(enc16 + ((size_t)s * NB + n) * 1024 + cc * 8);
                } else {
                    int r = c - 5120;
                    const f16* src = (r < 128) ? (xe_t + nrow + r * 8)
                                   : (r < 256) ? (h0 + nrow + (r - 128) * 8)
                                               : (h1 + nrow + (r - 256) * 8);
                    val[i] = *(const f16x8*)src;
                }
            }
        }
#pragma unroll
        for (int i = 0; i < IT; i++) {
            int c = tid + i * NTHR;
            if (c < TOT) {
                if (c < 5120) *(f16x8*)(lds + c * 16) = val[i];
                else          *(f16x8*)(lds + 81920 + (c - 5120) * 16) = val[i];
            }
        }
    }
    __syncthreads();

    if (w < 10) {
#pragma unroll
        for (int si = 0; si < 4; si++) {
            int s = w * 4 + si;
            const f16* wrow = attn_w + (size_t)s * 3072;
            float acc = 0.f;
#pragma unroll
            for (int jj = 0; jj < 6; jj++) {
                int j = lane + jj * 64;
                f16x8 a = *(const f16x8*)(lds + 81920 + j * 16);
                f16x8 b = *(const f16x8*)(wrow + j * 8);
#pragma unroll
                for (int e = 0; e < 8; e++)
                    acc = fmaf((float)a[e], (float)b[e], acc);
            }
            for (int o = 32; o; o >>= 1) acc += __shfl_down(acc, o);
            if (lane == 0) logit[s] = acc + attn_b[s];
        }
    }
    __syncthreads();

    if (w == 0) {
        float v = (lane < S_LEN) ? logit[lane] : -1e30f;
        float m = v;
        for (int o = 32; o; o >>= 1) m = fmaxf(m, __shfl_xor(m, o));
        float e = (lane < S_LEN) ? __expf(v - m) : 0.f;
        float sum = e;
        for (int o = 32; o; o >>= 1) sum += __shfl_xor(sum, o);
        if (lane < S_LEN) awls[lane] = e / sum;
    }
    __syncthreads();

    for (int col = tid; col < 1024; col += NTHR) {
        float acc = 0.f;
#pragma unroll
        for (int s = 0; s < S_LEN; s++)
            acc = fmaf(awls[s], (float)*(const f16*)(lds + s * 2048 + col * 2), acc);
        sysst_f16(appl + (size_t)n * 1024 + col, (f16)acc);
    }
}

// ---------------- comb phase: 256 blocks, 32x32 tiles, 12-way K split ------
__device__ void comb_phase(
    char* lds, int bid, int tid, const int* mr, const int* nc,
    const f16* __restrict__ xe_t, const f16* __restrict__ appl,
    const f16* __restrict__ Bw, const float* __restrict__ bias,
    f16* __restrict__ Cout) {
    const int cb = (bid & 31) * 32;
    const int rb = (bid >> 5) * 32;

    // ---- stage A = [xe | appl] (both plain cached): 32 x 4096B ----
    {
        constexpr int TOT = 8192;
        constexpr int IT = (TOT + NTHR - 1) / NTHR;   // 11
        f16x8 val[IT];
#pragma unroll
        for (int i = 0; i < IT; i++) {
            int c = tid + i * NTHR;
            if (c < TOT) {
                int row = c >> 8, cc = c & 255;
                const f16* src = (cc < 128)
                    ? (xe_t + (size_t)(rb + row) * 1024 + cc * 8)
                    : (appl + (size_t)(rb + row) * 1024 + (cc - 128) * 8);
                val[i] = *(const f16x8*)src;
            }
        }
#pragma unroll
        for (int i = 0; i < IT; i++) {
            int c = tid + i * NTHR;
            if (c < TOT) {
                int row = c >> 8, cc = c & 255;
                *(f16x8*)(lds + row * 4096 + ((cc ^ (row & 7)) << 4)) = val[i];
            }
        }
    }
    __syncthreads();

    const int w = tid >> 6, lane = tid & 63;
    const int r0 = lane & 15, kk0 = (lane >> 4) * 8;
    const int c0 = (w * 64) / 12, c1 = ((w + 1) * 64) / 12;
    const f16* B0 = Bw + (size_t)(cb + r0) * 2048 + kk0;
    const f16* B1 = Bw + (size_t)(cb + r0 + 16) * 2048 + kk0;
    const int swz = r0 & 7;
    const char* a0p = lds + r0 * 4096;
    const char* a1p = lds + (r0 + 16) * 4096;

    f32x4 acc00 = {0,0,0,0}, acc01 = {0,0,0,0}, acc10 = {0,0,0,0}, acc11 = {0,0,0,0};
    for (int c = c0; c < c1; c++) {
        int g = (c * 32 + kk0) >> 3;
        int off = (g ^ swz) << 4;
        f16x8 a0 = *(const f16x8*)(a0p + off);
        f16x8 a1 = *(const f16x8*)(a1p + off);
        f16x8 b0 = *(const f16x8*)(B0 + c * 32);
        f16x8 b1 = *(const f16x8*)(B1 + c * 32);
        acc00 = __builtin_amdgcn_mfma_f32_16x16x32_f16(a0, b0, acc00, 0, 0, 0);
        acc01 = __builtin_amdgcn_mfma_f32_16x16x32_f16(a0, b1, acc01, 0, 0, 0);
        acc10 = __builtin_amdgcn_mfma_f32_16x16x32_f16(a1, b0, acc10, 0, 0, 0);
        acc11 = __builtin_amdgcn_mfma_f32_16x16x32_f16(a1, b1, acc11, 0, 0, 0);
    }
    __syncthreads();

    float* red = (float*)lds;
    float* rw = red + w * 1024;
#pragma unroll
    for (int r = 0; r < 4; r++) {
        rw[mr[r] * 32 + nc[r]]             = acc00[r];
        rw[mr[r] * 32 + nc[r] + 16]        = acc01[r];
        rw[(mr[r] + 16) * 32 + nc[r]]      = acc10[r];
        rw[(mr[r] + 16) * 32 + nc[r] + 16] = acc11[r];
    }
    __syncthreads();

#pragma unroll
    for (int it = 0; it < 2; it++) {
        int i = tid + it * NTHR;
        if (i < 1024) {
            float s = 0.f;
#pragma unroll
            for (int p = 0; p < 12; p++) s += red[p * 1024 + i];
            int rr = i >> 5, ccn = i & 31;
            s += bias[cb + ccn];
            s = fmaxf(s, 0.f);
            sysst_f16(Cout + (size_t)(rb + rr) * 1024 + cb + ccn, (f16)s);
        }
    }
}

// ---------------- the mega kernel ------------------------------------------
__global__ __launch_bounds__(NTHR, 3) void k_mega(
    const f16* __restrict__ xe,
    f16* H0, f16* H1, float* hf,
    const f16* __restrict__ w_eih, const f16* __restrict__ w_ehh,
    const float* __restrict__ enc_bih, const float* __restrict__ enc_bhh,
    const f16* __restrict__ w_dih, const f16* __restrict__ w_dhh,
    const float* __restrict__ dec_bih, const float* __restrict__ dec_bhh,
    const f16* __restrict__ w_attn, const float* __restrict__ attn_b,
    const f16* __restrict__ w_comb, const float* __restrict__ comb_b,
    f16* XC, f16* AP,
    float* out, unsigned* sync) {
    __shared__ char smem[131584];
    __shared__ unsigned s_meta[4];
    char* lds = smem;
    const int bid = blockIdx.x;
    const int tid = threadIdx.x;
    const int lane = tid & 63;
    const size_t NH = (size_t)NB * HDIM;

    int mr[4], nc[4];
    probe_mn(lane, mr, nc);

    // ---- registration (for two-level barrier) ----
    if (tid == 0) {
        unsigned x;
        asm volatile("s_getreg_b32 %0, hwreg(20, 0, 32)" : "=s"(x));
        x &= 7;
        __hip_atomic_fetch_add(sync + 256 + x, 1u,
                               __ATOMIC_RELAXED, __HIP_MEMORY_SCOPE_AGENT);
        s_meta[0] = x;
    }
    __syncthreads();
    gbar1(sync + 512, sync + 513);
    if (tid == 0) {
        unsigned M = __hip_atomic_load(sync + 256 + s_meta[0],
                                       __ATOMIC_RELAXED, __HIP_MEMORY_SCOPE_AGENT);
        unsigned nx = 0;
        for (int i = 0; i < 8; i++)
            nx += (__hip_atomic_load(sync + 256 + i, __ATOMIC_RELAXED,
                                     __HIP_MEMORY_SCOPE_AGENT) > 0) ? 1u : 0u;
        s_meta[2] = M; s_meta[3] = nx;
    }
    __syncthreads();
    const unsigned xcd = s_meta[0], M = s_meta[2], NX = s_meta[3];

    float* h0f[2] = { hf, hf + 2 * NH };
    float* h1f[2] = { hf + NH, hf + 3 * NH };

    // ---- encoder: H0[t] -> H0[t+1], H1[t] -> H1[t+1]; enc_out = H1[1..40] --
    for (int t = 0; t < S_LEN; t++) {
        int p = t & 1;
        gru_phase(lds, bid, tid, mr, nc,
                  xe + (size_t)t * NB * EDIM,
                  H0 + (size_t)t * NH, h0f[p],
                  w_eih, w_ehh, enc_bih, enc_bhh,
                  H0 + (size_t)(t + 1) * NH, h0f[p ^ 1], (float*)nullptr);
        g2bar(sync, xcd, M, NX);
        gru_phase(lds, bid, tid, mr, nc,
                  H0 + (size_t)(t + 1) * NH,
                  H1 + (size_t)t * NH, h1f[p],
                  w_eih + (size_t)3 * HDIM * EDIM, w_ehh + (size_t)3 * HDIM * HDIM,
                  enc_bih + 3 * HDIM, enc_bhh + 3 * HDIM,
                  H1 + (size_t)(t + 1) * NH, h1f[p ^ 1], (float*)nullptr);
        g2bar(sync, xcd, M, NX);
    }

    // ---- decoder: global step g = 40+t ----
    for (int t = 0; t < S_LEN; t++) {
        int g = S_LEN + t;
        int p = g & 1;
        attn_phase(lds, bid, tid,
                   xe + (size_t)t * NB * EDIM,
                   H0 + (size_t)g * NH, H1 + (size_t)g * NH,
                   w_attn, attn_b, H1 + NH, AP + (size_t)t * NH);
        g2bar(sync, xcd, M, NX);
        comb_phase(lds, bid, tid, mr, nc,
                   xe + (size_t)t * NB * EDIM, AP + (size_t)t * NH,
                   w_comb, comb_b, XC + (size_t)t * NH);
        g2bar(sync, xcd, M, NX);
        gru_phase(lds, bid, tid, mr, nc,
                  XC + (size_t)t * NH,
                  H0 + (size_t)g * NH, h0f[p],
                  w_dih, w_dhh, dec_bih, dec_bhh,
                  H0 + (size_t)(g + 1) * NH, h0f[p ^ 1], (float*)nullptr);
        g2bar(sync, xcd, M, NX);
        gru_phase(lds, bid, tid, mr, nc,
                  H0 + (size_t)(g + 1) * NH,
                  H1 + (size_t)g * NH, h1f[p],
                  w_dih + (size_t)3 * HDIM * HDIM, w_dhh + (size_t)3 * HDIM * HDIM,
                  dec_bih + 3 * HDIM, dec_bhh + 3 * HDIM,
                  H1 + (size_t)(g + 1) * NH, h1f[p ^ 1], out + (size_t)t * NH);
        g2bar(sync, xcd, M, NX);
    }

    // ---- hT tail: finals are h0f[0], h1f[0] = hf[0 .. 2NH) ----
    if (tid < 512) {
        size_t idx = (size_t)bid * 512 + tid;
        f32x4 v;
        sysld_issue_f32x4(v, hf + idx * 4);
        sys_wait();
        sysst_f32x4(out + (size_t)S_LEN * NH + idx * 4, v);
    }
}

extern "C" void kernel_launch(void* const* d_in, const int* in_sizes, int n_in,
                              void* d_out, int out_size, void* d_ws, size_t ws_size,
                              hipStream_t stream) {
    const int*   tokens   = (const int*)d_in[0];
    const float* hidden   = (const float*)d_in[1];
    const float* emb      = (const float*)d_in[2];
    const float* enc_wih  = (const float*)d_in[3];
    const float* enc_whh  = (const float*)d_in[4];
    const float* enc_bih  = (const float*)d_in[5];
    const float* enc_bhh  = (const float*)d_in[6];
    const float* dec_wih  = (const float*)d_in[7];
    const float* dec_whh  = (const float*)d_in[8];
    const float* dec_bih  = (const float*)d_in[9];
    const float* dec_bhh  = (const float*)d_in[10];
    const float* attn_w   = (const float*)d_in[11];
    const float* attn_b   = (const float*)d_in[12];
    const float* comb_w   = (const float*)d_in[13];
    const float* comb_b   = (const float*)d_in[14];
    float* out = (float*)d_out;

    const size_t NH = (size_t)NB * HDIM;             // 262144
    const size_t WSZ = (size_t)2 * 3 * HDIM * EDIM;  // 6291456

    float* hf = (float*)d_ws;                        // 4*NH f32 ping-pong
    f16* wp = (f16*)(hf + 4 * NH);
    f16 *w_eih = wp;  wp += WSZ;
    f16 *w_ehh = wp;  wp += WSZ;
    f16 *w_dih = wp;  wp += WSZ;
    f16 *w_dhh = wp;  wp += WSZ;
    f16 *w_comb = wp; wp += (size_t)HDIM * 2048;
    f16 *w_attn = wp; wp += (size_t)S_LEN * 3072;
    f16 *xe = wp;     wp += (size_t)S_LEN * NB * EDIM;
    f16 *H0 = wp;     wp += (size_t)(2 * S_LEN + 1) * NH;  // chain t=0..80
    f16 *H1 = wp;     wp += (size_t)(2 * S_LEN + 1) * NH;  // chain t=0..80
    f16 *XC = wp;     wp += (size_t)S_LEN * NH;
    f16 *AP = wp;     wp += (size_t)S_LEN * NH;
    unsigned* syncp = (unsigned*)((((uintptr_t)wp) + 255) & ~(uintptr_t)255);

    k_init_sync<<<1, 256, 0, stream>>>(syncp);

    k_cvt4<<<(int)(WSZ / 4 / 256), 256, 0, stream>>>(enc_wih, w_eih, (int)(WSZ / 4));
    k_cvt4<<<(int)(WSZ / 4 / 256), 256, 0, stream>>>(enc_whh, w_ehh, (int)(WSZ / 4));
    k_cvt4<<<(int)(WSZ / 4 / 256), 256, 0, stream>>>(dec_wih, w_dih, (int)(WSZ / 4));
    k_cvt4<<<(int)(WSZ / 4 / 256), 256, 0, stream>>>(dec_whh, w_dhh, (int)(WSZ / 4));
    k_cvt4<<<(int)(HDIM * 2048 / 4 / 256), 256, 0, stream>>>(comb_w, w_comb,
                                                             HDIM * 2048 / 4);
    k_cvt4<<<(S_LEN * 3072 / 4 + 255) / 256, 256, 0, stream>>>(attn_w, w_attn,
                                                               S_LEN * 3072 / 4);
    k_embed_cvt<<<S_LEN * NB, 256, 0, stream>>>(tokens, emb, xe);
    // initial hidden -> H0[0], H1[0] (f16) and hf parity 0 (f32)
    k_cvt4<<<(int)(NH / 4 / 256), 256, 0, stream>>>(hidden, H0, (int)(NH / 4));
    k_cvt4<<<(int)(NH / 4 / 256), 256, 0, stream>>>(hidden + NH, H1, (int)(NH / 4));
    k_copyf4<<<(int)(NH / 4 / 256), 256, 0, stream>>>(hidden, hf, (int)(NH / 4));
    k_copyf4<<<(int)(NH / 4 / 256), 256, 0, stream>>>(hidden + NH, hf + NH, (int)(NH / 4));

    k_mega<<<NBLK, NTHR, 0, stream>>>(
        xe, H0, H1, hf,
        w_eih, w_ehh, enc_bih, enc_bhh,
        w_dih, w_dhh, dec_bih, dec_bhh,
        w_attn, attn_b, w_comb, comb_b,
        XC, AP, out, syncp);
}

// Round 15
// 5437.142 us; speedup vs baseline: 3.5916x; 1.0321x over previous
//
#include <hip/hip_runtime.h>
#include <hip/hip_bf16.h>

#define S_LEN 40
#define NB    256
#define EDIM  1024
#define HDIM  1024
#define NBLK  256
#define NTHR  768

typedef _Float16 f16;
typedef __attribute__((ext_vector_type(8))) _Float16 f16x8;
typedef __attribute__((ext_vector_type(4))) _Float16 f16x4;
typedef __attribute__((ext_vector_type(4))) float f32x4;

__device__ __forceinline__ float sigm(float x) {
    x = fminf(fmaxf(x, -30.f), 30.f);
    return 1.f / (1.f + __expf(-x));
}
__device__ __forceinline__ float tanh_fast(float x) {
    x = fminf(fmaxf(x, -15.f), 15.f);
    float e = __expf(2.f * x);
    return (e - 1.f) / (e + 1.f);
}

// ---- system-scope (cross-XCD write-through) helpers -----------------------
__device__ __forceinline__ void sysst_f16(f16* p, f16 v) {
    union { f16 f; unsigned short s; } u; u.f = v;
    unsigned int b = u.s;
    asm volatile("global_store_short %0, %1, off sc0 sc1" :: "v"(p), "v"(b) : "memory");
}

// ---- release-only single-counter barrier (registration only) --------------
__device__ __forceinline__ void gbar1(unsigned* cnt, unsigned* gen) {
    asm volatile("s_waitcnt vmcnt(0)" ::: "memory");
    __syncthreads();
    if (threadIdx.x == 0) {
        unsigned g = __hip_atomic_load(gen, __ATOMIC_RELAXED, __HIP_MEMORY_SCOPE_AGENT);
        unsigned a = __hip_atomic_fetch_add(cnt, 1u, __ATOMIC_RELEASE, __HIP_MEMORY_SCOPE_AGENT);
        if (a == NBLK - 1) {
            __hip_atomic_store(cnt, 0u, __ATOMIC_RELAXED, __HIP_MEMORY_SCOPE_AGENT);
            __hip_atomic_fetch_add(gen, 1u, __ATOMIC_RELEASE, __HIP_MEMORY_SCOPE_AGENT);
        } else {
            while (__hip_atomic_load(gen, __ATOMIC_RELAXED, __HIP_MEMORY_SCOPE_AGENT) == g)
                __builtin_amdgcn_s_sleep(2);
        }
    }
    __syncthreads();
}

// ---- two-level release-only grid barrier ----------------------------------
__device__ __forceinline__ void g2bar(unsigned* sync, unsigned xcd,
                                      unsigned M, unsigned NX) {
    asm volatile("s_waitcnt vmcnt(0)" ::: "memory");
    __syncthreads();
    if (threadIdx.x == 0) {
        unsigned* ggen = sync;
        unsigned* gcnt = sync + 1;
        unsigned* xa = sync + 16 + xcd * 16;
        unsigned g = __hip_atomic_load(ggen, __ATOMIC_RELAXED, __HIP_MEMORY_SCOPE_AGENT);
        unsigned a = __hip_atomic_fetch_add(xa, 1u, __ATOMIC_RELEASE, __HIP_MEMORY_SCOPE_AGENT);
        if (a == M - 1) {
            __hip_atomic_store(xa, 0u, __ATOMIC_RELAXED, __HIP_MEMORY_SCOPE_AGENT);
            unsigned b = __hip_atomic_fetch_add(gcnt, 1u, __ATOMIC_RELEASE, __HIP_MEMORY_SCOPE_AGENT);
            if (b == NX - 1) {
                __hip_atomic_store(gcnt, 0u, __ATOMIC_RELAXED, __HIP_MEMORY_SCOPE_AGENT);
                __hip_atomic_fetch_add(ggen, 1u, __ATOMIC_RELEASE, __HIP_MEMORY_SCOPE_AGENT);
            } else {
                while (__hip_atomic_load(ggen, __ATOMIC_RELAXED, __HIP_MEMORY_SCOPE_AGENT) == g)
                    __builtin_amdgcn_s_sleep(4);
            }
        } else {
            while (__hip_atomic_load(ggen, __ATOMIC_RELAXED, __HIP_MEMORY_SCOPE_AGENT) == g)
                __builtin_amdgcn_s_sleep(4);
        }
    }
    __syncthreads();
}

__global__ void k_init_sync(unsigned* s) {
    for (int k = threadIdx.x; k < 1024; k += 256) s[k] = 0;
}

// Layout-robust probe: A[i][k]=i, B[k][j]=1/32 -> D[i][j]=i.
__device__ __forceinline__ void probe_mn(int lane, int* mrow, int* ncol) {
    f16x8 pa, pb;
#pragma unroll
    for (int e = 0; e < 8; e++) {
        pa[e] = (f16)(float)(lane & 15);
        pb[e] = (f16)0.03125f;
    }
    f32x4 pacc = {0, 0, 0, 0};
    pacc = __builtin_amdgcn_mfma_f32_16x16x32_f16(pa, pb, pacc, 0, 0, 0);
#pragma unroll
    for (int r = 0; r < 4; r++) {
        int m = (int)(pacc[r] + 0.5f);
        int cg = ((lane >> 4) << 2) + r;
        mrow[r] = m;
        ncol[r] = (m == cg) ? (lane & 15) : cg;
    }
}

// ---------------- pre-kernels ----------------------------------------------
__global__ __launch_bounds__(256) void k_cvt4(const float* __restrict__ src,
                                              f16* __restrict__ dst, int n4) {
    int i = blockIdx.x * 256 + threadIdx.x;
    if (i < n4) {
        f32x4 v = ((const f32x4*)src)[i];
        f16x4 o = {(f16)v.x, (f16)v.y, (f16)v.z, (f16)v.w};
        ((f16x4*)dst)[i] = o;
    }
}
__global__ __launch_bounds__(256) void k_embed_cvt(const int* __restrict__ tok,
                                                   const float* __restrict__ emb,
                                                   f16* __restrict__ xe) {
    int b = blockIdx.x;
    int t = threadIdx.x;
    int token = tok[b];
    f32x4 v = ((const f32x4*)(emb + (size_t)token * EDIM))[t];
    f16x4 o = {(f16)v.x, (f16)v.y, (f16)v.z, (f16)v.w};
    ((f16x4*)(xe + (size_t)b * EDIM))[t] = o;
}

// ---------------- GRU phase: 256 blocks, 32x32 tiles, 12 waves -------------
// h_prev for the epilogue comes from the LDS h-stage (f16) — no f32 master.
__device__ void gru_phase(
    char* lds, int bid, int tid, const int* mr, const int* nc,
    const f16* __restrict__ xsrc, const f16* __restrict__ hsrc,
    const f16* __restrict__ wih, const f16* __restrict__ whh,
    const float* __restrict__ bih, const float* __restrict__ bhh,
    f16* ho16, float* of_step, float* of_fin) {
    const int cb = (bid & 31) * 32;
    const int rb = (bid >> 5) * 32;

    // ---- stage A (x 64KB + h 64KB) into LDS, swizzled (plain cached) ----
    {
        constexpr int TOT = 8192;
        constexpr int IT = (TOT + NTHR - 1) / NTHR;   // 11
        f16x8 val[IT];
#pragma unroll
        for (int i = 0; i < IT; i++) {
            int c = tid + i * NTHR;
            if (c < TOT) {
                int isH = c >> 12;
                int cl = c & 4095;
                int row = cl >> 7, cc = cl & 127;
                const f16* src = (isH ? hsrc : xsrc) +
                                 (size_t)(rb + row) * 1024 + cc * 8;
                val[i] = *(const f16x8*)src;
            }
        }
#pragma unroll
        for (int i = 0; i < IT; i++) {
            int c = tid + i * NTHR;
            if (c < TOT) {
                int isH = c >> 12;
                int cl = c & 4095;
                int row = cl >> 7, cc = cl & 127;
                *(f16x8*)(lds + isH * 65536 + row * 2048 +
                          ((cc ^ (row & 7)) << 4)) = val[i];
            }
        }
    }
    __syncthreads();

    // ---- K loop: A from LDS, B (weights) from L2-hot global ----
    const int w = tid >> 6, lane = tid & 63;
    const int pair = w >> 1, kh = w & 1;
    const int gate = (pair >= 3) ? pair - 3 : pair;
    const int r0 = lane & 15, kk0 = (lane >> 4) * 8;
    const f16* B = ((pair < 3) ? wih : whh) + ((size_t)gate * HDIM + cb) * 1024;
    const f16* B0 = B + (size_t)r0 * 1024 + kk0 + kh * 512;
    const f16* B1 = B + (size_t)(r0 + 16) * 1024 + kk0 + kh * 512;
    const int abase = (pair < 3) ? 0 : 65536;
    const int swz = r0 & 7;
    const char* a0p = lds + abase + r0 * 2048;
    const char* a1p = lds + abase + (r0 + 16) * 2048;

    f32x4 acc00 = {0,0,0,0}, acc01 = {0,0,0,0}, acc10 = {0,0,0,0}, acc11 = {0,0,0,0};
#pragma unroll 4
    for (int k = 0; k < 512; k += 32) {
        int g = (kh * 512 + kk0 + k) >> 3;
        int off = (g ^ swz) << 4;
        f16x8 a0 = *(const f16x8*)(a0p + off);
        f16x8 a1 = *(const f16x8*)(a1p + off);
        f16x8 b0 = *(const f16x8*)(B0 + k);
        f16x8 b1 = *(const f16x8*)(B1 + k);
        acc00 = __builtin_amdgcn_mfma_f32_16x16x32_f16(a0, b0, acc00, 0, 0, 0);
        acc01 = __builtin_amdgcn_mfma_f32_16x16x32_f16(a0, b1, acc01, 0, 0, 0);
        acc10 = __builtin_amdgcn_mfma_f32_16x16x32_f16(a1, b0, acc10, 0, 0, 0);
        acc11 = __builtin_amdgcn_mfma_f32_16x16x32_f16(a1, b1, acc11, 0, 0, 0);
    }
    __syncthreads();

    float* red = (float*)lds;       // overlaps x-stage (first 48KB), h intact
    float* rw = red + w * 1024;
#pragma unroll
    for (int r = 0; r < 4; r++) {
        rw[mr[r] * 32 + nc[r]]             = acc00[r];
        rw[mr[r] * 32 + nc[r] + 16]        = acc01[r];
        rw[(mr[r] + 16) * 32 + nc[r]]      = acc10[r];
        rw[(mr[r] + 16) * 32 + nc[r] + 16] = acc11[r];
    }
    __syncthreads();

    // ---- epilogue: h_prev read from LDS h-stage ----
#pragma unroll
    for (int it = 0; it < 2; it++) {
        int i = tid + it * NTHR;
        if (i < 1024) {
            int rr = i >> 5, ccn = i & 31;
            int col = cb + ccn;
            int row = rb + rr;
            float gir = red[i]         + red[1024 + i];
            float giz = red[2048 + i]  + red[3072 + i];
            float gin = red[4096 + i]  + red[5120 + i];
            float ghr = red[6144 + i]  + red[7168 + i];
            float ghz = red[8192 + i]  + red[9216 + i];
            float ghn = red[10240 + i] + red[11264 + i];
            float r = sigm(gir + bih[col] + ghr + bhh[col]);
            float z = sigm(giz + bih[HDIM + col] + ghz + bhh[HDIM + col]);
            float n = tanh_fast(gin + bih[2 * HDIM + col] +
                                r * (ghn + bhh[2 * HDIM + col]));
            int gidx = col >> 3, within = col & 7;
            float hp = (float)*(const f16*)(lds + 65536 + rr * 2048 +
                                            ((gidx ^ (rr & 7)) << 4) + within * 2);
            float hn2 = (1.f - z) * n + z * hp;
            size_t idx = (size_t)row * HDIM + col;
            sysst_f16(ho16 + idx, (f16)hn2);
            if (of_step) of_step[idx] = hn2;   // plain (kernel-end flush)
            if (of_fin)  of_fin[idx] = hn2;
        }
    }
}

// ---------------- attention phase: 256 blocks = 256 batch rows -------------
__device__ void attn_phase(
    char* lds, int bid, int tid,
    const f16* __restrict__ xe_t, const f16* __restrict__ h0,
    const f16* __restrict__ h1,
    const f16* __restrict__ attn_w, const float* __restrict__ attn_b,
    const f16* __restrict__ enc16, f16* __restrict__ appl) {
    float* logit = (float*)(lds + 131072);
    float* awls  = logit + 64;
    const int n = bid;
    const int w = tid >> 6, lane = tid & 63;
    const size_t nrow = (size_t)n * 1024;

    {
        constexpr int TOT = 5504;
        constexpr int IT = (TOT + NTHR - 1) / NTHR;  // 8
        f16x8 val[IT];
#pragma unroll
        for (int i = 0; i < IT; i++) {
            int c = tid + i * NTHR;
            if (c < TOT) {
                if (c < 5120) {
                    int s = c >> 7, cc = c & 127;
                    val[i] = *(const f16x8*)(enc16 + ((size_t)s * NB + n) * 1024 + cc * 8);
                } else {
                    int r = c - 5120;
                    const f16* src = (r < 128) ? (xe_t + nrow + r * 8)
                                   : (r < 256) ? (h0 + nrow + (r - 128) * 8)
                                               : (h1 + nrow + (r - 256) * 8);
                    val[i] = *(const f16x8*)src;
                }
            }
        }
#pragma unroll
        for (int i = 0; i < IT; i++) {
            int c = tid + i * NTHR;
            if (c < TOT) {
                if (c < 5120) *(f16x8*)(lds + c * 16) = val[i];
                else          *(f16x8*)(lds + 81920 + (c - 5120) * 16) = val[i];
            }
        }
    }
    __syncthreads();

    if (w < 10) {
#pragma unroll
        for (int si = 0; si < 4; si++) {
            int s = w * 4 + si;
            const f16* wrow = attn_w + (size_t)s * 3072;
            float acc = 0.f;
#pragma unroll
            for (int jj = 0; jj < 6; jj++) {
                int j = lane + jj * 64;
                f16x8 a = *(const f16x8*)(lds + 81920 + j * 16);
                f16x8 b = *(const f16x8*)(wrow + j * 8);
#pragma unroll
                for (int e = 0; e < 8; e++)
                    acc = fmaf((float)a[e], (float)b[e], acc);
            }
            for (int o = 32; o; o >>= 1) acc += __shfl_down(acc, o);
            if (lane == 0) logit[s] = acc + attn_b[s];
        }
    }
    __syncthreads();

    if (w == 0) {
        float v = (lane < S_LEN) ? logit[lane] : -1e30f;
        float m = v;
        for (int o = 32; o; o >>= 1) m = fmaxf(m, __shfl_xor(m, o));
        float e = (lane < S_LEN) ? __expf(v - m) : 0.f;
        float sum = e;
        for (int o = 32; o; o >>= 1) sum += __shfl_xor(sum, o);
        if (lane < S_LEN) awls[lane] = e / sum;
    }
    __syncthreads();

    for (int col = tid; col < 1024; col += NTHR) {
        float acc = 0.f;
#pragma unroll
        for (int s = 0; s < S_LEN; s++)
            acc = fmaf(awls[s], (float)*(const f16*)(lds + s * 2048 + col * 2), acc);
        sysst_f16(appl + (size_t)n * 1024 + col, (f16)acc);
    }
}

// ---------------- comb phase: 256 blocks, 32x32 tiles, 12-way K split ------
__device__ void comb_phase(
    char* lds, int bid, int tid, const int* mr, const int* nc,
    const f16* __restrict__ xe_t, const f16* __restrict__ appl,
    const f16* __restrict__ Bw, const float* __restrict__ bias,
    f16* __restrict__ Cout) {
    const int cb = (bid & 31) * 32;
    const int rb = (bid >> 5) * 32;

    {
        constexpr int TOT = 8192;
        constexpr int IT = (TOT + NTHR - 1) / NTHR;   // 11
        f16x8 val[IT];
#pragma unroll
        for (int i = 0; i < IT; i++) {
            int c = tid + i * NTHR;
            if (c < TOT) {
                int row = c >> 8, cc = c & 255;
                const f16* src = (cc < 128)
                    ? (xe_t + (size_t)(rb + row) * 1024 + cc * 8)
                    : (appl + (size_t)(rb + row) * 1024 + (cc - 128) * 8);
                val[i] = *(const f16x8*)src;
            }
        }
#pragma unroll
        for (int i = 0; i < IT; i++) {
            int c = tid + i * NTHR;
            if (c < TOT) {
                int row = c >> 8, cc = c & 255;
                *(f16x8*)(lds + row * 4096 + ((cc ^ (row & 7)) << 4)) = val[i];
            }
        }
    }
    __syncthreads();

    const int w = tid >> 6, lane = tid & 63;
    const int r0 = lane & 15, kk0 = (lane >> 4) * 8;
    const int c0 = (w * 64) / 12, c1 = ((w + 1) * 64) / 12;
    const f16* B0 = Bw + (size_t)(cb + r0) * 2048 + kk0;
    const f16* B1 = Bw + (size_t)(cb + r0 + 16) * 2048 + kk0;
    const int swz = r0 & 7;
    const char* a0p = lds + r0 * 4096;
    const char* a1p = lds + (r0 + 16) * 4096;

    f32x4 acc00 = {0,0,0,0}, acc01 = {0,0,0,0}, acc10 = {0,0,0,0}, acc11 = {0,0,0,0};
    for (int c = c0; c < c1; c++) {
        int g = (c * 32 + kk0) >> 3;
        int off = (g ^ swz) << 4;
        f16x8 a0 = *(const f16x8*)(a0p + off);
        f16x8 a1 = *(const f16x8*)(a1p + off);
        f16x8 b0 = *(const f16x8*)(B0 + c * 32);
        f16x8 b1 = *(const f16x8*)(B1 + c * 32);
        acc00 = __builtin_amdgcn_mfma_f32_16x16x32_f16(a0, b0, acc00, 0, 0, 0);
        acc01 = __builtin_amdgcn_mfma_f32_16x16x32_f16(a0, b1, acc01, 0, 0, 0);
        acc10 = __builtin_amdgcn_mfma_f32_16x16x32_f16(a1, b0, acc10, 0, 0, 0);
        acc11 = __builtin_amdgcn_mfma_f32_16x16x32_f16(a1, b1, acc11, 0, 0, 0);
    }
    __syncthreads();

    float* red = (float*)lds;
    float* rw = red + w * 1024;
#pragma unroll
    for (int r = 0; r < 4; r++) {
        rw[mr[r] * 32 + nc[r]]             = acc00[r];
        rw[mr[r] * 32 + nc[r] + 16]        = acc01[r];
        rw[(mr[r] + 16) * 32 + nc[r]]      = acc10[r];
        rw[(mr[r] + 16) * 32 + nc[r] + 16] = acc11[r];
    }
    __syncthreads();

#pragma unroll
    for (int it = 0; it < 2; it++) {
        int i = tid + it * NTHR;
        if (i < 1024) {
            float s = 0.f;
#pragma unroll
            for (int p = 0; p < 12; p++) s += red[p * 1024 + i];
            int rr = i >> 5, ccn = i & 31;
            s += bias[cb + ccn];
            s = fmaxf(s, 0.f);
            sysst_f16(Cout + (size_t)(rb + rr) * 1024 + cb + ccn, (f16)s);
        }
    }
}

// ---------------- the mega kernel ------------------------------------------
__global__ __launch_bounds__(NTHR, 3) void k_mega(
    const f16* __restrict__ xe,
    f16* H0, f16* H1,
    const f16* __restrict__ w_eih, const f16* __restrict__ w_ehh,
    const float* __restrict__ enc_bih, const float* __restrict__ enc_bhh,
    const f16* __restrict__ w_dih, const f16* __restrict__ w_dhh,
    const float* __restrict__ dec_bih, const float* __restrict__ dec_bhh,
    const f16* __restrict__ w_attn, const float* __restrict__ attn_b,
    const f16* __restrict__ w_comb, const float* __restrict__ comb_b,
    f16* XC, f16* AP,
    float* out, unsigned* sync) {
    __shared__ char smem[131584];
    __shared__ unsigned s_meta[4];
    char* lds = smem;
    const int bid = blockIdx.x;
    const int tid = threadIdx.x;
    const int lane = tid & 63;
    const size_t NH = (size_t)NB * HDIM;

    int mr[4], nc[4];
    probe_mn(lane, mr, nc);

    // ---- registration (for two-level barrier) ----
    if (tid == 0) {
        unsigned x;
        asm volatile("s_getreg_b32 %0, hwreg(20, 0, 32)" : "=s"(x));
        x &= 7;
        __hip_atomic_fetch_add(sync + 256 + x, 1u,
                               __ATOMIC_RELAXED, __HIP_MEMORY_SCOPE_AGENT);
        s_meta[0] = x;
    }
    __syncthreads();
    gbar1(sync + 512, sync + 513);
    if (tid == 0) {
        unsigned M = __hip_atomic_load(sync + 256 + s_meta[0],
                                       __ATOMIC_RELAXED, __HIP_MEMORY_SCOPE_AGENT);
        unsigned nx = 0;
        for (int i = 0; i < 8; i++)
            nx += (__hip_atomic_load(sync + 256 + i, __ATOMIC_RELAXED,
                                     __HIP_MEMORY_SCOPE_AGENT) > 0) ? 1u : 0u;
        s_meta[2] = M; s_meta[3] = nx;
    }
    __syncthreads();
    const unsigned xcd = s_meta[0], M = s_meta[2], NX = s_meta[3];

    // ---- encoder, layer-major: all l0 steps, then all l1 steps ----
    for (int t = 0; t < S_LEN; t++) {
        gru_phase(lds, bid, tid, mr, nc,
                  xe + (size_t)t * NB * EDIM, H0 + (size_t)t * NH,
                  w_eih, w_ehh, enc_bih, enc_bhh,
                  H0 + (size_t)(t + 1) * NH, (float*)nullptr, (float*)nullptr);
        g2bar(sync, xcd, M, NX);
    }
    for (int t = 0; t < S_LEN; t++) {
        gru_phase(lds, bid, tid, mr, nc,
                  H0 + (size_t)(t + 1) * NH, H1 + (size_t)t * NH,
                  w_eih + (size_t)3 * HDIM * EDIM, w_ehh + (size_t)3 * HDIM * HDIM,
                  enc_bih + 3 * HDIM, enc_bhh + 3 * HDIM,
                  H1 + (size_t)(t + 1) * NH, (float*)nullptr, (float*)nullptr);
        g2bar(sync, xcd, M, NX);
    }

    // ---- decoder: global step g = 40+t ----
    for (int t = 0; t < S_LEN; t++) {
        int g = S_LEN + t;
        attn_phase(lds, bid, tid,
                   xe + (size_t)t * NB * EDIM,
                   H0 + (size_t)g * NH, H1 + (size_t)g * NH,
                   w_attn, attn_b, H1 + NH, AP + (size_t)t * NH);
        g2bar(sync, xcd, M, NX);
        comb_phase(lds, bid, tid, mr, nc,
                   xe + (size_t)t * NB * EDIM, AP + (size_t)t * NH,
                   w_comb, comb_b, XC + (size_t)t * NH);
        g2bar(sync, xcd, M, NX);
        gru_phase(lds, bid, tid, mr, nc,
                  XC + (size_t)t * NH, H0 + (size_t)g * NH,
                  w_dih, w_dhh, dec_bih, dec_bhh,
                  H0 + (size_t)(g + 1) * NH, (float*)nullptr,
                  (t == S_LEN - 1) ? (out + (size_t)S_LEN * NH) : (float*)nullptr);
        g2bar(sync, xcd, M, NX);
        gru_phase(lds, bid, tid, mr, nc,
                  H0 + (size_t)(g + 1) * NH, H1 + (size_t)g * NH,
                  w_dih + (size_t)3 * HDIM * HDIM, w_dhh + (size_t)3 * HDIM * HDIM,
                  dec_bih + 3 * HDIM, dec_bhh + 3 * HDIM,
                  H1 + (size_t)(g + 1) * NH, out + (size_t)t * NH,
                  (t == S_LEN - 1) ? (out + (size_t)(S_LEN + 1) * NH) : (float*)nullptr);
        g2bar(sync, xcd, M, NX);
    }
}

extern "C" void kernel_launch(void* const* d_in, const int* in_sizes, int n_in,
                              void* d_out, int out_size, void* d_ws, size_t ws_size,
                              hipStream_t stream) {
    const int*   tokens   = (const int*)d_in[0];
    const float* hidden   = (const float*)d_in[1];
    const float* emb      = (const float*)d_in[2];
    const float* enc_wih  = (const float*)d_in[3];
    const float* enc_whh  = (const float*)d_in[4];
    const float* enc_bih  = (const float*)d_in[5];
    const float* enc_bhh  = (const float*)d_in[6];
    const float* dec_wih  = (const float*)d_in[7];
    const float* dec_whh  = (const float*)d_in[8];
    const float* dec_bih  = (const float*)d_in[9];
    const float* dec_bhh  = (const float*)d_in[10];
    const float* attn_w   = (const float*)d_in[11];
    const float* attn_b   = (const float*)d_in[12];
    const float* comb_w   = (const float*)d_in[13];
    const float* comb_b   = (const float*)d_in[14];
    float* out = (float*)d_out;

    const size_t NH = (size_t)NB * HDIM;             // 262144
    const size_t WSZ = (size_t)2 * 3 * HDIM * EDIM;  // 6291456

    f16* wp = (f16*)d_ws;
    f16 *w_eih = wp;  wp += WSZ;
    f16 *w_ehh = wp;  wp += WSZ;
    f16 *w_dih = wp;  wp += WSZ;
    f16 *w_dhh = wp;  wp += WSZ;
    f16 *w_comb = wp; wp += (size_t)HDIM * 2048;
    f16 *w_attn = wp; wp += (size_t)S_LEN * 3072;
    f16 *xe = wp;     wp += (size_t)S_LEN * NB * EDIM;
    f16 *H0 = wp;     wp += (size_t)(2 * S_LEN + 1) * NH;  // chain t=0..80
    f16 *H1 = wp;     wp += (size_t)(2 * S_LEN + 1) * NH;  // chain t=0..80
    f16 *XC = wp;     wp += (size_t)S_LEN * NH;
    f16 *AP = wp;     wp += (size_t)S_LEN * NH;
    unsigned* syncp = (unsigned*)((((uintptr_t)wp) + 255) & ~(uintptr_t)255);

    k_init_sync<<<1, 256, 0, stream>>>(syncp);

    k_cvt4<<<(int)(WSZ / 4 / 256), 256, 0, stream>>>(enc_wih, w_eih, (int)(WSZ / 4));
    k_cvt4<<<(int)(WSZ / 4 / 256), 256, 0, stream>>>(enc_whh, w_ehh, (int)(WSZ / 4));
    k_cvt4<<<(int)(WSZ / 4 / 256), 256, 0, stream>>>(dec_wih, w_dih, (int)(WSZ / 4));
    k_cvt4<<<(int)(WSZ / 4 / 256), 256, 0, stream>>>(dec_whh, w_dhh, (int)(WSZ / 4));
    k_cvt4<<<(int)(HDIM * 2048 / 4 / 256), 256, 0, stream>>>(comb_w, w_comb,
                                                             HDIM * 2048 / 4);
    k_cvt4<<<(S_LEN * 3072 / 4 + 255) / 256, 256, 0, stream>>>(attn_w, w_attn,
                                                               S_LEN * 3072 / 4);
    k_embed_cvt<<<S_LEN * NB, 256, 0, stream>>>(tokens, emb, xe);
    // initial hidden -> H0[0], H1[0] (f16)
    k_cvt4<<<(int)(NH / 4 / 256), 256, 0, stream>>>(hidden, H0, (int)(NH / 4));
    k_cvt4<<<(int)(NH / 4 / 256), 256, 0, stream>>>(hidden + NH, H1, (int)(NH / 4));

    k_mega<<<NBLK, NTHR, 0, stream>>>(
        xe, H0, H1,
        w_eih, w_ehh, enc_bih, enc_bhh,
        w_dih, w_dhh, dec_bih, dec_bhh,
        w_attn, attn_b, w_comb, comb_b,
        XC, AP, out, syncp);
}